// Round 1
// baseline (367.516 us; speedup 1.0000x reference)
//
#include <hip/hip_runtime.h>
#include <hip/hip_bf16.h>
#include <stdint.h>

// MoELoRALinear: out = x@W^T + b + sum_e softmax(x@rw^T)_e * SCALE * (x@A_e^T)@B_e^T
// M=8192 (B*S), K=2048, N=2048, E=4, R=8. SCALE = 16/8 = 2.
#define M_ROWS 8192
#define KDIM   2048
#define NDIM   2048
#define SCALE_F 2.0f

typedef __attribute__((ext_vector_type(8))) short  bf16x8;
typedef __attribute__((ext_vector_type(4))) float  f32x4;
typedef __attribute__((ext_vector_type(4))) unsigned short u16x4;

__device__ __forceinline__ unsigned short f2bf(float f) {
    unsigned u = __float_as_uint(f);
    unsigned r = (u + 0x7fffu + ((u >> 16) & 1u)) >> 16;  // RNE
    return (unsigned short)r;
}

#define GLOAD_LDS16(gptr, lptr) \
    __builtin_amdgcn_global_load_lds((const __attribute__((address_space(1))) void*)(gptr), \
                                     (__attribute__((address_space(3))) void*)(lptr), 16, 0, 0)

// ---------------------------------------------------------------------------
// Kernel 1: per-row — convert x to bf16, compute 32 LoRA down-proj dots +
// 4 router dots (fp32), softmax gates, write gated proj Wg (bf16 [M][32]).
// 256 thr = 4 waves; each wave owns 2 rows. grid = 8192/8 = 1024.
// ---------------------------------------------------------------------------
__global__ __launch_bounds__(256) void k_rowprep(
    const float* __restrict__ x,      // [M][2048]
    const float* __restrict__ A,      // [32][2048]  (e*8+r rows)
    const float* __restrict__ rw,     // [4][2048]
    unsigned short* __restrict__ xb,  // [M][2048] bf16
    unsigned short* __restrict__ Wg)  // [M][32]   bf16 (gate*SCALE*proj)
{
    const int tid = threadIdx.x;
    const int l = tid & 63, w = tid >> 6;
    const int row0 = blockIdx.x * 8 + w * 2;

    const float4* x4 = (const float4*)x;
    const float4* A4 = (const float4*)A;
    const float4* r4 = (const float4*)rw;

    float accA[36], accB[36];
#pragma unroll
    for (int v = 0; v < 36; ++v) { accA[v] = 0.f; accB[v] = 0.f; }

    for (int j = 0; j < 8; ++j) {           // 8 x float4*64lanes = 2048 elems
        const int ofs = j * 64 + l;
        float4 xa = x4[(size_t)row0 * 512 + ofs];
        float4 xc = x4[(size_t)(row0 + 1) * 512 + ofs];

        // store bf16 x (coalesced 8B/lane)
        u16x4 sa = { f2bf(xa.x), f2bf(xa.y), f2bf(xa.z), f2bf(xa.w) };
        u16x4 sc = { f2bf(xc.x), f2bf(xc.y), f2bf(xc.z), f2bf(xc.w) };
        *(u16x4*)(xb + (size_t)row0 * 2048 + ofs * 4) = sa;
        *(u16x4*)(xb + (size_t)(row0 + 1) * 2048 + ofs * 4) = sc;

#pragma unroll
        for (int v = 0; v < 36; ++v) {
            float4 wv = (v < 32) ? A4[(size_t)v * 512 + ofs]
                                 : r4[(size_t)(v - 32) * 512 + ofs];
            accA[v] += xa.x * wv.x + xa.y * wv.y + xa.z * wv.z + xa.w * wv.w;
            accB[v] += xc.x * wv.x + xc.y * wv.y + xc.z * wv.z + xc.w * wv.w;
        }
    }

    // butterfly reduce all 72 partials across the 64-lane wave
#pragma unroll
    for (int v = 0; v < 36; ++v) {
        float a = accA[v], b = accB[v];
#pragma unroll
        for (int s = 1; s < 64; s <<= 1) {
            a += __shfl_xor(a, s);
            b += __shfl_xor(b, s);
        }
        accA[v] = a; accB[v] = b;
    }

    // softmax over 4 router logits, * SCALE
    float gA0, gA1, gA2, gA3, gB0, gB1, gB2, gB3;
    {
        float m = fmaxf(fmaxf(accA[32], accA[33]), fmaxf(accA[34], accA[35]));
        float e0 = __expf(accA[32] - m), e1 = __expf(accA[33] - m);
        float e2 = __expf(accA[34] - m), e3 = __expf(accA[35] - m);
        float inv = SCALE_F / (e0 + e1 + e2 + e3);
        gA0 = e0 * inv; gA1 = e1 * inv; gA2 = e2 * inv; gA3 = e3 * inv;
    }
    {
        float m = fmaxf(fmaxf(accB[32], accB[33]), fmaxf(accB[34], accB[35]));
        float e0 = __expf(accB[32] - m), e1 = __expf(accB[33] - m);
        float e2 = __expf(accB[34] - m), e3 = __expf(accB[35] - m);
        float inv = SCALE_F / (e0 + e1 + e2 + e3);
        gB0 = e0 * inv; gB1 = e1 * inv; gB2 = e2 * inv; gB3 = e3 * inv;
    }

    // select-tree: pa = accA[li], pb = accB[li] (li = l&31), register-only
    const int li = l & 31;
    float pa = accA[0], pb = accB[0];
#pragma unroll
    for (int i = 1; i < 32; ++i) {
        pa = (li == i) ? accA[i] : pa;
        pb = (li == i) ? accB[i] : pb;
    }
    const int ge = li >> 3;
    float ga = (ge == 0) ? gA0 : (ge == 1) ? gA1 : (ge == 2) ? gA2 : gA3;
    float gb = (ge == 0) ? gB0 : (ge == 1) ? gB1 : (ge == 2) ? gB2 : gB3;

    float val = (l < 32) ? ga * pa : gb * pb;
    int   row = row0 + ((l < 32) ? 0 : 1);
    Wg[(size_t)row * 32 + li] = f2bf(val);
}

// ---------------------------------------------------------------------------
// Kernel 2: convert base_w -> bf16 [o][k]; scatter B[e][o][r] -> Bc[o][e*8+r].
// ---------------------------------------------------------------------------
__global__ __launch_bounds__(256) void k_wconv(
    const float* __restrict__ bw,      // [2048][2048]
    const float* __restrict__ Bm,      // [4][2048][8]
    unsigned short* __restrict__ wb,   // [2048][2048] bf16
    unsigned short* __restrict__ Bc)   // [2048][32]   bf16
{
    int t = blockIdx.x * 256 + threadIdx.x;
    const float4* s4 = (const float4*)bw;
    for (int i = t; i < (2048 * 2048 / 4); i += gridDim.x * 256) {
        float4 v = s4[i];
        u16x4 o = { f2bf(v.x), f2bf(v.y), f2bf(v.z), f2bf(v.w) };
        *(u16x4*)(wb + (size_t)i * 4) = o;
    }
    if (t < 4 * 2048 * 8) {
        int e = t >> 14, rem = t & 16383, o = rem >> 3, r = rem & 7;
        Bc[o * 32 + e * 8 + r] = f2bf(Bm[t]);
    }
}

// ---------------------------------------------------------------------------
// Kernel 3: main GEMM (m97 structure): 128x128 tile, BK=32, 4 waves, each
// wave 64x64 via 4x4 frags of mfma_f32_16x16x32_bf16; global_load_lds
// width-16 staging; fused LoRA rank-32 epilogue + bias; fp32 out.
// grid = (8192/128)*(2048/128) = 64*16 = 1024, XCD-swizzled.
// ---------------------------------------------------------------------------
__global__ __launch_bounds__(256) void k_gemm(
    const unsigned short* __restrict__ xb,   // [M][2048] bf16
    const unsigned short* __restrict__ wb,   // [N][2048] bf16
    const unsigned short* __restrict__ Wg,   // [M][32]   bf16
    const unsigned short* __restrict__ Bc,   // [N][32]   bf16
    const float* __restrict__ bias,          // [N]
    float* __restrict__ out)                 // [M][N] fp32
{
    __shared__ unsigned short As[128 * 32];
    __shared__ unsigned short Bs[128 * 32];

    const int tid = threadIdx.x;
    const int l = tid & 63, w = tid >> 6;

    const int bid = blockIdx.x;
    const int swz = (bid & 7) * 128 + (bid >> 3);   // 1024 wg, 8 XCDs
    const int mt = swz & 63, nt = swz >> 6;
    const int m0 = mt * 128, n0 = nt * 128;
    const int wr = w >> 1, wc = w & 1;              // 2x2 wave grid

    const int arow = l >> 2;          // row-in-chunk (16 rows per 1KB chunk)
    const int akc  = (l & 3) * 8;     // k-element offset (8 bf16 = 16B)

    f32x4 acc[4][4];
#pragma unroll
    for (int m = 0; m < 4; ++m)
#pragma unroll
        for (int n = 0; n < 4; ++n)
            acc[m][n] = (f32x4){0.f, 0.f, 0.f, 0.f};

    for (int kt = 0; kt < KDIM / 32; ++kt) {
        const int k0 = kt * 32;
#pragma unroll
        for (int t = 0; t < 2; ++t) {
            const int c = w * 2 + t;               // chunk 0..7 (1KB each)
            const unsigned short* ga = xb + (size_t)(m0 + c * 16 + arow) * KDIM + k0 + akc;
            GLOAD_LDS16(ga, As + c * 512);
            const unsigned short* gb = wb + (size_t)(n0 + c * 16 + arow) * KDIM + k0 + akc;
            GLOAD_LDS16(gb, Bs + c * 512);
        }
        __syncthreads();

        bf16x8 a[4], b[4];
#pragma unroll
        for (int m = 0; m < 4; ++m)
            a[m] = *(const bf16x8*)&As[(wr * 64 + m * 16 + (l & 15)) * 32 + (l >> 4) * 8];
#pragma unroll
        for (int n = 0; n < 4; ++n)
            b[n] = *(const bf16x8*)&Bs[(wc * 64 + n * 16 + (l & 15)) * 32 + (l >> 4) * 8];
#pragma unroll
        for (int m = 0; m < 4; ++m)
#pragma unroll
            for (int n = 0; n < 4; ++n)
                acc[m][n] = __builtin_amdgcn_mfma_f32_16x16x32_bf16(a[m], b[n], acc[m][n], 0, 0, 0);
        __syncthreads();
    }

    // ---- fused LoRA epilogue: one K=32 MFMA step with Wg (A) and Bc (B) ----
    {
#pragma unroll
        for (int t = 0; t < 2; ++t) {
            const int c = w * 2 + t;               // 8 chunks of 1KB = [128][32]
            const unsigned short* gw = Wg + (size_t)(m0 + c * 16 + arow) * 32 + akc;
            GLOAD_LDS16(gw, As + c * 512);
            const unsigned short* gc = Bc + (size_t)(n0 + c * 16 + arow) * 32 + akc;
            GLOAD_LDS16(gc, Bs + c * 512);
        }
        __syncthreads();

        bf16x8 a[4], b[4];
#pragma unroll
        for (int m = 0; m < 4; ++m)
            a[m] = *(const bf16x8*)&As[(wr * 64 + m * 16 + (l & 15)) * 32 + (l >> 4) * 8];
#pragma unroll
        for (int n = 0; n < 4; ++n)
            b[n] = *(const bf16x8*)&Bs[(wc * 64 + n * 16 + (l & 15)) * 32 + (l >> 4) * 8];
#pragma unroll
        for (int m = 0; m < 4; ++m)
#pragma unroll
            for (int n = 0; n < 4; ++n)
                acc[m][n] = __builtin_amdgcn_mfma_f32_16x16x32_bf16(a[m], b[n], acc[m][n], 0, 0, 0);
    }

    // ---- epilogue: bias + store fp32 ----
#pragma unroll
    for (int n = 0; n < 4; ++n) {
        const int cn = n0 + wc * 64 + n * 16 + (l & 15);
        const float bv = bias[cn];
#pragma unroll
        for (int m = 0; m < 4; ++m) {
            const int rm = m0 + wr * 64 + m * 16 + (l >> 4) * 4;
#pragma unroll
            for (int j = 0; j < 4; ++j)
                out[(size_t)(rm + j) * NDIM + cn] = acc[m][n][j] + bv;
        }
    }
}

// ---------------------------------------------------------------------------
extern "C" void kernel_launch(void* const* d_in, const int* in_sizes, int n_in,
                              void* d_out, int out_size, void* d_ws, size_t ws_size,
                              hipStream_t stream) {
    const float* x      = (const float*)d_in[0];
    const float* base_w = (const float*)d_in[1];
    const float* base_b = (const float*)d_in[2];
    const float* A      = (const float*)d_in[3];
    const float* Bm     = (const float*)d_in[4];
    const float* rw     = (const float*)d_in[5];
    float* out = (float*)d_out;

    char* ws = (char*)d_ws;
    unsigned short* xb = (unsigned short*)(ws);                    // 33,554,432 B
    unsigned short* wb = (unsigned short*)(ws + 33554432);         //  8,388,608 B
    unsigned short* Wg = (unsigned short*)(ws + 33554432 + 8388608);          // 524,288 B
    unsigned short* Bc = (unsigned short*)(ws + 33554432 + 8388608 + 524288); // 131,072 B

    k_rowprep<<<dim3(1024), dim3(256), 0, stream>>>(x, A, rw, xb, Wg);
    k_wconv  <<<dim3(1024), dim3(256), 0, stream>>>(base_w, Bm, wb, Bc);
    k_gemm   <<<dim3(1024), dim3(256), 0, stream>>>(xb, wb, Wg, Bc, base_b, out);
}

// Round 3
// 222.139 us; speedup vs baseline: 1.6544x; 1.6544x over previous
//
#include <hip/hip_runtime.h>
#include <hip/hip_bf16.h>
#include <stdint.h>

// MoELoRALinear: out = x@W^T + b + sum_e softmax(x@rw^T)_e * SCALE * (x@A_e^T)@B_e^T
// M=8192, K=2048, N=2048, E=4, R=8. SCALE = 2.
#define M_ROWS 8192
#define KDIM   2048
#define NDIM   2048
#define SCALE_F 2.0f

typedef __attribute__((ext_vector_type(8))) short  bf16x8;
typedef __attribute__((ext_vector_type(4))) float  f32x4;
typedef __attribute__((ext_vector_type(4))) unsigned short u16x4;

__device__ __forceinline__ unsigned short f2bf(float f) {
    unsigned u = __float_as_uint(f);
    unsigned r = (u + 0x7fffu + ((u >> 16) & 1u)) >> 16;  // RNE
    return (unsigned short)r;
}

#define GLOAD_LDS16(gptr, lptr) \
    __builtin_amdgcn_global_load_lds((const __attribute__((address_space(1))) void*)(gptr), \
                                     (__attribute__((address_space(3))) void*)(lptr), 16, 0, 0)

// ---------------------------------------------------------------------------
// Kernel 1: streaming converts. x->bf16 xb; base_w->bf16 wb; pack
// W36[48][2048] = [A(32); rw(4); zeros(12)] bf16; scatter B -> Bc[o][32].
// ---------------------------------------------------------------------------
__global__ __launch_bounds__(256) void k_convert(
    const float* __restrict__ x,
    const float* __restrict__ bw,
    const float* __restrict__ A,
    const float* __restrict__ rw,
    const float* __restrict__ Bm,
    unsigned short* __restrict__ xb,
    unsigned short* __restrict__ wb,
    unsigned short* __restrict__ W36,
    unsigned short* __restrict__ Bc)
{
    const int t = blockIdx.x * 256 + threadIdx.x;
    const int nthr = gridDim.x * 256;

    const float4* x4 = (const float4*)x;
    for (int i = t; i < (M_ROWS * KDIM / 4); i += nthr) {
        float4 v = x4[i];
        u16x4 o = { f2bf(v.x), f2bf(v.y), f2bf(v.z), f2bf(v.w) };
        *(u16x4*)(xb + (size_t)i * 4) = o;
    }
    const float4* w4 = (const float4*)bw;
    for (int i = t; i < (NDIM * KDIM / 4); i += nthr) {
        float4 v = w4[i];
        u16x4 o = { f2bf(v.x), f2bf(v.y), f2bf(v.z), f2bf(v.w) };
        *(u16x4*)(wb + (size_t)i * 4) = o;
    }
    if (t < 48 * 2048) {
        int row = t >> 11, col = t & 2047;
        float v = (row < 32) ? A[row * 2048 + col]
                : (row < 36) ? rw[(row - 32) * 2048 + col] : 0.f;
        W36[t] = f2bf(v);
    }
    if (t < 4 * 2048 * 8) {
        int e = t >> 14, rem = t & 16383, o = rem >> 3, r = rem & 7;
        Bc[o * 32 + e * 8 + r] = f2bf(Bm[t]);
    }
}

// ---------------------------------------------------------------------------
// Kernel 2: skinny MFMA GEMM P[8192][48] = xb @ W36^T, BK=64, XOR-swizzled
// LDS, fused softmax-gate epilogue -> Wg[M][32] = gate_e * SCALE * proj.
// 64-row M-tile, 4 waves (wave w: rows w*16..w*16+15). grid = 128.
// ---------------------------------------------------------------------------
__global__ __launch_bounds__(256) void k_proj(
    const unsigned short* __restrict__ xb,   // [8192][2048] bf16
    const unsigned short* __restrict__ W36,  // [48][2048]   bf16
    unsigned short* __restrict__ Wg)         // [8192][32]   bf16
{
    __shared__ unsigned short As[64 * 64];   // 8KB
    __shared__ unsigned short Ws[48 * 64];   // 6KB

    const int tid = threadIdx.x;
    const int l = tid & 63, w = tid >> 6;
    const int l15 = l & 15, l16h = l >> 4, l7 = l & 7;
    const int m0 = blockIdx.x * 64;
    const int st_col = ((l & 7) ^ (l >> 3)) * 8;   // pre-swizzled global col

    f32x4 acc[3];
#pragma unroll
    for (int n = 0; n < 3; ++n) acc[n] = (f32x4){0.f, 0.f, 0.f, 0.f};

    for (int kt = 0; kt < KDIM / 64; ++kt) {
        const int k0 = kt * 64;
        {   // A-tile: wave w stages rows w*16..+15 (2 issues of 8 rows)
            unsigned short* lp = As + w * 1024;
            const unsigned short* gp = xb + (size_t)(m0 + w * 16 + (l >> 3)) * KDIM + k0 + st_col;
            GLOAD_LDS16(gp, lp);
            GLOAD_LDS16(gp + (size_t)8 * KDIM, lp + 512);
        }
        if (w < 3) {  // W-tile: 48 rows
            unsigned short* lp = Ws + w * 1024;
            const unsigned short* gp = W36 + (size_t)(w * 16 + (l >> 3)) * KDIM + k0 + st_col;
            GLOAD_LDS16(gp, lp);
            GLOAD_LDS16(gp + (size_t)8 * KDIM, lp + 512);
        }
        __syncthreads();

#pragma unroll
        for (int kk = 0; kk < 2; ++kk) {
            const int arow = w * 16 + l15;
            bf16x8 a = *(const bf16x8*)&As[arow * 64 + (((kk * 4 + l16h) ^ l7) << 3)];
#pragma unroll
            for (int n = 0; n < 3; ++n) {
                const int brow = n * 16 + l15;
                bf16x8 b = *(const bf16x8*)&Ws[brow * 64 + (((kk * 4 + l16h) ^ l7) << 3)];
                acc[n] = __builtin_amdgcn_mfma_f32_16x16x32_bf16(a, b, acc[n], 0, 0, 0);
            }
        }
        __syncthreads();
    }

    // fused gating epilogue. C/D: col=l&15, row=(l>>4)*4+j. cols 32..35 = logits.
#pragma unroll
    for (int j = 0; j < 4; ++j) {
        const int base = l & 48;
        float lg0 = __shfl(acc[2][j], base + 0);
        float lg1 = __shfl(acc[2][j], base + 1);
        float lg2 = __shfl(acc[2][j], base + 2);
        float lg3 = __shfl(acc[2][j], base + 3);
        float mx = fmaxf(fmaxf(lg0, lg1), fmaxf(lg2, lg3));
        float e0 = __expf(lg0 - mx), e1 = __expf(lg1 - mx);
        float e2 = __expf(lg2 - mx), e3 = __expf(lg3 - mx);
        float inv = SCALE_F / (e0 + e1 + e2 + e3);
        float g0 = e0 * inv, g1 = e1 * inv, g2 = e2 * inv, g3 = e3 * inv;

        const int row = m0 + w * 16 + (l >> 4) * 4 + j;
#pragma unroll
        for (int n = 0; n < 2; ++n) {
            const int cn = n * 16 + l15;
            const int e = cn >> 3;
            float g = (e == 0) ? g0 : (e == 1) ? g1 : (e == 2) ? g2 : g3;
            Wg[(size_t)row * 32 + cn] = f2bf(g * acc[n][j]);
        }
    }
}

// ---------------------------------------------------------------------------
// Kernel 3: 256x256 8-phase GEMM (T2+T3+T4+T5). BK=64, 512 thr (8 waves 2x4),
// 128KB dyn LDS: A slots [buf][half] = [2][2][128][64] bf16 at shorts 0..32768,
// B same at 32768..65536. XOR swizzle: 16B-unit ^= (row&7), pre-swizzled on
// the global source (gload_lds dest linear), same XOR on ds_read.
// Schedule per window j (computing tile j, buf j&1):
//   q0 (A-h0 x B-h0): stage Bh1(j+1);  q1 (A-h1 x B-h0): stage Ah1(j+1)
//   q2 (A-h0 x B-h1): stage Bh0(j+2);  q3 (A-h1 x B-h1): stage Ah0(j+2),
//       then s_waitcnt vmcnt(4) (two half-tiles in flight), barriers raw.
// Fused LoRA (K=32) + bias epilogue. grid = 256 (1 block/CU), XCD-chunked.
// ---------------------------------------------------------------------------
#define GPHASE(JB, Q, STAGE_STMT, CKPT_STMT) do {                              \
    bf16x8 afr_[4][2];                                                         \
    _Pragma("unroll") for (int mi = 0; mi < 4; ++mi) {                         \
      const int row_ = wr * 64 + mi * 16 + l15;                                \
      const int ab_ = (JB) * 16384 + ((Q) & 1) * 8192 + row_ * 64;             \
      _Pragma("unroll") for (int kk = 0; kk < 2; ++kk)                         \
        afr_[mi][kk] = *(const bf16x8*)&S[ab_ + (((kk * 4 + l16h) ^ l7) << 3)];\
    }                                                                          \
    if (((Q) & 1) == 0) {                                                      \
      _Pragma("unroll") for (int ni = 0; ni < 2; ++ni) {                       \
        const int row_ = wc * 32 + ni * 16 + l15;                              \
        const int bb_ = 32768 + (JB) * 16384 + ((Q) >> 1) * 8192 + row_ * 64;  \
        _Pragma("unroll") for (int kk = 0; kk < 2; ++kk)                       \
          bfr[ni][kk] = *(const bf16x8*)&S[bb_ + (((kk * 4 + l16h) ^ l7) << 3)];\
      }                                                                        \
    }                                                                          \
    STAGE_STMT                                                                 \
    CKPT_STMT                                                                  \
    __builtin_amdgcn_s_barrier();                                              \
    __builtin_amdgcn_s_setprio(1);                                             \
    _Pragma("unroll") for (int mi = 0; mi < 4; ++mi)                           \
      _Pragma("unroll") for (int ni = 0; ni < 2; ++ni)                         \
        _Pragma("unroll") for (int kk = 0; kk < 2; ++kk)                       \
          acc[((Q) & 1) * 4 + mi][((Q) >> 1) * 2 + ni] =                       \
            __builtin_amdgcn_mfma_f32_16x16x32_bf16(afr_[mi][kk], bfr[ni][kk], \
              acc[((Q) & 1) * 4 + mi][((Q) >> 1) * 2 + ni], 0, 0, 0);          \
    __builtin_amdgcn_s_setprio(0);                                             \
    __builtin_amdgcn_s_barrier();                                              \
  } while (0)

__global__ __launch_bounds__(512, 2) void k_gemm(
    const unsigned short* __restrict__ xb,   // [M][2048] bf16
    const unsigned short* __restrict__ wb,   // [N][2048] bf16
    const unsigned short* __restrict__ Wg,   // [M][32]   bf16
    const unsigned short* __restrict__ Bc,   // [N][32]   bf16
    const float* __restrict__ bias,          // [N]
    float* __restrict__ out)                 // [M][N] fp32
{
    extern __shared__ unsigned short S[];    // 65536 shorts = 128KB

    const int tid = threadIdx.x;
    const int l = tid & 63, w = tid >> 6;
    const int l15 = l & 15, l16h = l >> 4, l7 = l & 7;
    const int wr = w >> 2, wc = w & 3;

    // XCD-chunked swizzle: 256 blocks, 8 XCDs -> 32 contiguous tiles each.
    const int bid = blockIdx.x;
    const int tile = (bid & 7) * 32 + (bid >> 3);
    const int mt = tile >> 3, nt = tile & 7;
    const int m0 = mt * 256, n0 = nt * 256;

    const int st_row = w * 8 + (l >> 3);           // row within 64-row issue
    const int st_col = ((l & 7) ^ (l >> 3)) * 8;   // pre-swizzled k offset

    auto stageA = [&](int t, int h) {
        unsigned short* lp = S + ((t & 1) * 16384 + h * 8192 + w * 512);
        const unsigned short* gp = xb + (size_t)(m0 + h * 128 + st_row) * KDIM + t * 64 + st_col;
        GLOAD_LDS16(gp, lp);
        GLOAD_LDS16(gp + (size_t)64 * KDIM, lp + 4096);
    };
    auto stageB = [&](int t, int h) {
        unsigned short* lp = S + (32768 + (t & 1) * 16384 + h * 8192 + w * 512);
        const unsigned short* gp = wb + (size_t)(n0 + h * 128 + st_row) * KDIM + t * 64 + st_col;
        GLOAD_LDS16(gp, lp);
        GLOAD_LDS16(gp + (size_t)64 * KDIM, lp + 4096);
    };

    f32x4 acc[8][4];
#pragma unroll
    for (int m = 0; m < 8; ++m)
#pragma unroll
        for (int n = 0; n < 4; ++n)
            acc[m][n] = (f32x4){0.f, 0.f, 0.f, 0.f};
    bf16x8 bfr[2][2];

    // prologue: tile0 full + Bh0(1), Ah0(1); wait tile0 landed (4 loads out)
    stageA(0, 0); stageA(0, 1); stageB(0, 0); stageB(0, 1);
    stageB(1, 0); stageA(1, 0);
    asm volatile("s_waitcnt vmcnt(4)" ::: "memory");
    __builtin_amdgcn_s_barrier();

#pragma unroll 2
    for (int j = 0; j < 32; ++j) {
        const int jb = j & 1;
        GPHASE(jb, 0, { if (j < 31) stageB(j + 1, 1); }, );
        GPHASE(jb, 1, { if (j < 31) stageA(j + 1, 1); }, );
        GPHASE(jb, 2, { if (j < 30) stageB(j + 2, 0); }, );
        GPHASE(jb, 3, { if (j < 30) stageA(j + 2, 0); },
               { if (j < 30) { asm volatile("s_waitcnt vmcnt(4)" ::: "memory"); }
                 else        { asm volatile("s_waitcnt vmcnt(0)" ::: "memory"); } });
    }

    // ---- fused LoRA: stage Wg[256][32] + Bc[256][32] linear, one K=32 step
    {
        const int lw_row = w * 16 + (l >> 2);
        const int lw_col = (l & 3) * 8;
        unsigned short* lpA = S + w * 512;
        const unsigned short* gpA = Wg + (size_t)(m0 + lw_row) * 32 + lw_col;
        GLOAD_LDS16(gpA, lpA);
        GLOAD_LDS16(gpA + (size_t)128 * 32, lpA + 4096);
        unsigned short* lpB = S + 32768 + w * 512;
        const unsigned short* gpB = Bc + (size_t)(n0 + lw_row) * 32 + lw_col;
        GLOAD_LDS16(gpB, lpB);
        GLOAD_LDS16(gpB + (size_t)128 * 32, lpB + 4096);
    }
    asm volatile("s_waitcnt vmcnt(0)" ::: "memory");
    __builtin_amdgcn_s_barrier();

#pragma unroll
    for (int m = 0; m < 8; ++m) {
        bf16x8 af = *(const bf16x8*)&S[((m >> 2) * 128 + wr * 64 + (m & 3) * 16 + l15) * 32 + l16h * 8];
#pragma unroll
        for (int n = 0; n < 4; ++n) {
            bf16x8 bf = *(const bf16x8*)&S[32768 + ((n >> 1) * 128 + wc * 32 + (n & 1) * 16 + l15) * 32 + l16h * 8];
            acc[m][n] = __builtin_amdgcn_mfma_f32_16x16x32_bf16(af, bf, acc[m][n], 0, 0, 0);
        }
    }

    // ---- bias + store fp32 ----
#pragma unroll
    for (int n = 0; n < 4; ++n) {
        const int cn = n0 + (n >> 1) * 128 + wc * 32 + (n & 1) * 16 + l15;
        const float bv = bias[cn];
#pragma unroll
        for (int m = 0; m < 8; ++m) {
            const int rm = m0 + (m >> 2) * 128 + wr * 64 + (m & 3) * 16 + l16h * 4;
#pragma unroll
            for (int jj = 0; jj < 4; ++jj)
                out[(size_t)(rm + jj) * NDIM + cn] = acc[m][n][jj] + bv;
        }
    }
}

// ---------------------------------------------------------------------------
extern "C" void kernel_launch(void* const* d_in, const int* in_sizes, int n_in,
                              void* d_out, int out_size, void* d_ws, size_t ws_size,
                              hipStream_t stream) {
    const float* x      = (const float*)d_in[0];
    const float* base_w = (const float*)d_in[1];
    const float* base_b = (const float*)d_in[2];
    const float* A      = (const float*)d_in[3];
    const float* Bm     = (const float*)d_in[4];
    const float* rw     = (const float*)d_in[5];
    float* out = (float*)d_out;

    char* ws = (char*)d_ws;
    unsigned short* xb  = (unsigned short*)(ws);                            // 33,554,432 B
    unsigned short* wb  = (unsigned short*)(ws + 33554432);                 //  8,388,608 B
    unsigned short* W36 = (unsigned short*)(ws + 33554432 + 8388608);       //    196,608 B
    unsigned short* Wg  = (unsigned short*)(ws + 33554432 + 8388608 + 196608);           // 524,288 B
    unsigned short* Bc  = (unsigned short*)(ws + 33554432 + 8388608 + 196608 + 524288);  // 131,072 B

    k_convert<<<dim3(2048), dim3(256), 0,      stream>>>(x, base_w, A, rw, Bm, xb, wb, W36, Bc);
    k_proj   <<<dim3(128),  dim3(256), 0,      stream>>>(xb, W36, Wg);
    k_gemm   <<<dim3(256),  dim3(512), 131072, stream>>>(xb, wb, Wg, Bc, base_b, out);
}

// Round 4
// 218.924 us; speedup vs baseline: 1.6787x; 1.0147x over previous
//
#include <hip/hip_runtime.h>
#include <hip/hip_bf16.h>
#include <stdint.h>

// MoELoRALinear: out = x@W^T + b + sum_e softmax(x@rw^T)_e * SCALE * (x@A_e^T)@B_e^T
// M=8192, K=2048, N=2048, E=4, R=8. SCALE = 2.
#define M_ROWS 8192
#define KDIM   2048
#define NDIM   2048
#define SCALE_F 2.0f

typedef __attribute__((ext_vector_type(8))) short  bf16x8;
typedef __attribute__((ext_vector_type(4))) float  f32x4;
typedef __attribute__((ext_vector_type(8))) unsigned short u16x8;

__device__ __forceinline__ unsigned short f2bf(float f) {
    unsigned u = __float_as_uint(f);
    unsigned r = (u + 0x7fffu + ((u >> 16) & 1u)) >> 16;  // RNE
    return (unsigned short)r;
}

#define GLOAD_LDS16(gptr, lptr) \
    __builtin_amdgcn_global_load_lds((const __attribute__((address_space(1))) void*)(gptr), \
                                     (__attribute__((address_space(3))) void*)(lptr), 16, 0, 0)

// ---------------------------------------------------------------------------
// Kernel 1: streaming converts, all 16B stores. x->xb bf16; base_w->wb bf16;
// pack W36[48][2048] = [A(32); rw(4); zeros(12)]; Bm[e][o][r] -> Bc[o][e*8+r].
// ---------------------------------------------------------------------------
__global__ __launch_bounds__(256) void k_convert(
    const float* __restrict__ x,
    const float* __restrict__ bw,
    const float* __restrict__ A,
    const float* __restrict__ rw,
    const float* __restrict__ Bm,
    unsigned short* __restrict__ xb,
    unsigned short* __restrict__ wb,
    unsigned short* __restrict__ W36,
    unsigned short* __restrict__ Bc)
{
    const int t = blockIdx.x * 256 + threadIdx.x;
    const int nthr = gridDim.x * 256;

    for (int i = t; i < (M_ROWS * KDIM / 8); i += nthr) {
        float4 v0 = *(const float4*)(x + (size_t)i * 8);
        float4 v1 = *(const float4*)(x + (size_t)i * 8 + 4);
        u16x8 o = { f2bf(v0.x), f2bf(v0.y), f2bf(v0.z), f2bf(v0.w),
                    f2bf(v1.x), f2bf(v1.y), f2bf(v1.z), f2bf(v1.w) };
        *(u16x8*)(xb + (size_t)i * 8) = o;
    }
    for (int i = t; i < (NDIM * KDIM / 8); i += nthr) {
        float4 v0 = *(const float4*)(bw + (size_t)i * 8);
        float4 v1 = *(const float4*)(bw + (size_t)i * 8 + 4);
        u16x8 o = { f2bf(v0.x), f2bf(v0.y), f2bf(v0.z), f2bf(v0.w),
                    f2bf(v1.x), f2bf(v1.y), f2bf(v1.z), f2bf(v1.w) };
        *(u16x8*)(wb + (size_t)i * 8) = o;
    }
    if (t < 48 * 2048 / 8) {
        const int row = (t * 8) >> 11, col = (t * 8) & 2047;
        u16x8 o;
        if (row < 36) {
            const float* src = (row < 32) ? (A + (size_t)row * 2048 + col)
                                          : (rw + (size_t)(row - 32) * 2048 + col);
            float4 v0 = *(const float4*)(src);
            float4 v1 = *(const float4*)(src + 4);
            o = (u16x8){ f2bf(v0.x), f2bf(v0.y), f2bf(v0.z), f2bf(v0.w),
                         f2bf(v1.x), f2bf(v1.y), f2bf(v1.z), f2bf(v1.w) };
        } else {
            o = (u16x8){0, 0, 0, 0, 0, 0, 0, 0};
        }
        *(u16x8*)(W36 + (size_t)t * 8) = o;
    }
    if (t < 4 * 2048) {   // one 8-wide rank-row per thread
        const int e = t >> 11, o = t & 2047;
        const float* src = Bm + ((size_t)e * 2048 + o) * 8;
        float4 v0 = *(const float4*)(src);
        float4 v1 = *(const float4*)(src + 4);
        u16x8 ov = { f2bf(v0.x), f2bf(v0.y), f2bf(v0.z), f2bf(v0.w),
                     f2bf(v1.x), f2bf(v1.y), f2bf(v1.z), f2bf(v1.w) };
        *(u16x8*)(Bc + (size_t)o * 32 + e * 8) = ov;
    }
}

// ---------------------------------------------------------------------------
// Kernel 2: skinny GEMM P[8192][48] = xb @ W36^T, fully register-resident:
// 1 wave per 16 rows, fragments loaded straight from global (4-lane groups
// cover contiguous 64B -> coalesced; W36 is L2-resident). No LDS, no
// barriers -> compiler software-pipelines. Fused softmax gate epilogue.
// grid = 512 x 64 threads.
// ---------------------------------------------------------------------------
__global__ __launch_bounds__(64) void k_proj(
    const unsigned short* __restrict__ xb,   // [8192][2048] bf16
    const unsigned short* __restrict__ W36,  // [48][2048]   bf16
    unsigned short* __restrict__ Wg)         // [8192][32]   bf16
{
    const int l = threadIdx.x;
    const int l15 = l & 15, l16h = l >> 4;
    const int row0 = blockIdx.x * 16;

    const unsigned short* pa = xb + (size_t)(row0 + l15) * KDIM + l16h * 8;
    const unsigned short* pb0 = W36 + (size_t)(0 * 16 + l15) * KDIM + l16h * 8;
    const unsigned short* pb1 = W36 + (size_t)(1 * 16 + l15) * KDIM + l16h * 8;
    const unsigned short* pb2 = W36 + (size_t)(2 * 16 + l15) * KDIM + l16h * 8;

    f32x4 acc[3];
#pragma unroll
    for (int n = 0; n < 3; ++n) acc[n] = (f32x4){0.f, 0.f, 0.f, 0.f};

#pragma unroll 4
    for (int kt = 0; kt < KDIM / 32; ++kt) {
        bf16x8 a = *(const bf16x8*)(pa + kt * 32);
        bf16x8 b0 = *(const bf16x8*)(pb0 + kt * 32);
        bf16x8 b1 = *(const bf16x8*)(pb1 + kt * 32);
        bf16x8 b2 = *(const bf16x8*)(pb2 + kt * 32);
        acc[0] = __builtin_amdgcn_mfma_f32_16x16x32_bf16(a, b0, acc[0], 0, 0, 0);
        acc[1] = __builtin_amdgcn_mfma_f32_16x16x32_bf16(a, b1, acc[1], 0, 0, 0);
        acc[2] = __builtin_amdgcn_mfma_f32_16x16x32_bf16(a, b2, acc[2], 0, 0, 0);
    }

    // fused gating. C/D: col=l&15, row=(l>>4)*4+j. acc[2] cols 32..35 = logits.
#pragma unroll
    for (int j = 0; j < 4; ++j) {
        const int base = l & 48;
        float lg0 = __shfl(acc[2][j], base + 0);
        float lg1 = __shfl(acc[2][j], base + 1);
        float lg2 = __shfl(acc[2][j], base + 2);
        float lg3 = __shfl(acc[2][j], base + 3);
        float mx = fmaxf(fmaxf(lg0, lg1), fmaxf(lg2, lg3));
        float e0 = __expf(lg0 - mx), e1 = __expf(lg1 - mx);
        float e2 = __expf(lg2 - mx), e3 = __expf(lg3 - mx);
        float inv = SCALE_F / (e0 + e1 + e2 + e3);
        float g0 = e0 * inv, g1 = e1 * inv, g2 = e2 * inv, g3 = e3 * inv;

        const int row = row0 + l16h * 4 + j;
#pragma unroll
        for (int n = 0; n < 2; ++n) {
            const int cn = n * 16 + l15;
            const int e = cn >> 3;
            float g = (e == 0) ? g0 : (e == 1) ? g1 : (e == 2) ? g2 : g3;
            Wg[(size_t)row * 32 + cn] = f2bf(g * acc[n][j]);
        }
    }
}

// ---------------------------------------------------------------------------
// Kernel 3: 256x256 8-phase GEMM. BK=64, 512 thr (8 waves 2x4), 128KB LDS.
// Gray-code quadrant order so each A-half is ds_read ONCE per K-tile and
// both B-half fragment sets persist in regs: reads/phase = 12/4/8/0.
//   q0=(Ah0,Bh0): rd Ah0+Bh0, stage B(j+1,h1)
//   q1=(Ah0,Bh1): rd Bh1,     stage A(j+1,h1)
//   q2=(Ah1,Bh0): rd Ah1,     stage B(j+2,h0)   [Bh0 LDS last read @q0 -> safe]
//   q3=(Ah1,Bh1): rd none,    stage A(j+2,h0), ckpt vmcnt(4)
// ckpt drains tile j+1 fully (leftover h0 from j-1 + this iter's h1).
// Swizzle: 16B-unit ^= row&7, pre-swizzled global src + same XOR on reads.
// Fused LoRA (K=32) + bias epilogue. grid = 256, XCD-chunked.
// ---------------------------------------------------------------------------
#define PH(JB, AH, BH, DO_ARD, DO_BRD, STAGE_STMT, CKPT_STMT) do {             \
    if (DO_ARD) {                                                              \
      _Pragma("unroll") for (int mi = 0; mi < 4; ++mi) {                       \
        afr[mi][0] = *(const bf16x8*)&S[(JB)*16384 + (AH)*8192 + mi*1024 + aoff0]; \
        afr[mi][1] = *(const bf16x8*)&S[(JB)*16384 + (AH)*8192 + mi*1024 + aoff1]; \
      }                                                                        \
    }                                                                          \
    if (DO_BRD) {                                                              \
      _Pragma("unroll") for (int ni = 0; ni < 2; ++ni) {                       \
        bfr[BH][ni][0] = *(const bf16x8*)&Sb[(JB)*16384 + (BH)*8192 + ni*1024 + boff0]; \
        bfr[BH][ni][1] = *(const bf16x8*)&Sb[(JB)*16384 + (BH)*8192 + ni*1024 + boff1]; \
      }                                                                        \
    }                                                                          \
    STAGE_STMT                                                                 \
    CKPT_STMT                                                                  \
    __builtin_amdgcn_s_barrier();                                              \
    __builtin_amdgcn_s_setprio(1);                                             \
    _Pragma("unroll") for (int mi = 0; mi < 4; ++mi)                           \
      _Pragma("unroll") for (int ni = 0; ni < 2; ++ni) {                       \
        acc[(AH)*4+mi][(BH)*2+ni] = __builtin_amdgcn_mfma_f32_16x16x32_bf16(   \
            afr[mi][0], bfr[BH][ni][0], acc[(AH)*4+mi][(BH)*2+ni], 0, 0, 0);   \
        acc[(AH)*4+mi][(BH)*2+ni] = __builtin_amdgcn_mfma_f32_16x16x32_bf16(   \
            afr[mi][1], bfr[BH][ni][1], acc[(AH)*4+mi][(BH)*2+ni], 0, 0, 0);   \
      }                                                                        \
    __builtin_amdgcn_s_setprio(0);                                             \
    __builtin_amdgcn_s_barrier();                                              \
  } while (0)

__global__ __launch_bounds__(512, 2) void k_gemm(
    const unsigned short* __restrict__ xb,   // [M][2048] bf16
    const unsigned short* __restrict__ wb,   // [N][2048] bf16
    const unsigned short* __restrict__ Wg,   // [M][32]   bf16
    const unsigned short* __restrict__ Bc,   // [N][32]   bf16
    const float* __restrict__ bias,          // [N]
    float* __restrict__ out)                 // [M][N] fp32
{
    extern __shared__ unsigned short S[];    // 65536 shorts = 128KB
    unsigned short* Sb = S + 32768;

    const int tid = threadIdx.x;
    const int l = tid & 63, w = tid >> 6;
    const int l15 = l & 15, l16h = l >> 4, l7 = l & 7;
    const int wr = w >> 2, wc = w & 3;

    // XCD-chunked swizzle: 256 blocks, 8 XCDs -> 32 contiguous tiles each.
    const int bid = blockIdx.x;
    const int tile = (bid & 7) * 32 + (bid >> 3);
    const int mt = tile >> 3, nt = tile & 7;
    const int m0 = mt * 256, n0 = nt * 256;

    // hoisted lane offsets (shorts): fragment reads
    const int aoff0 = (wr * 64 + l15) * 64 + ((l16h ^ l7) << 3);
    const int aoff1 = (wr * 64 + l15) * 64 + (((4 + l16h) ^ l7) << 3);
    const int boff0 = (wc * 32 + l15) * 64 + ((l16h ^ l7) << 3);
    const int boff1 = (wc * 32 + l15) * 64 + (((4 + l16h) ^ l7) << 3);

    // staging: row/col within 64-row issue, pre-swizzled global col
    const int st_row = w * 8 + (l >> 3);
    const int st_col = ((l & 7) ^ (l >> 3)) * 8;
    const unsigned short* gA0 = xb + (size_t)(m0 + st_row) * KDIM + st_col;
    const unsigned short* gB0 = wb + (size_t)(n0 + st_row) * KDIM + st_col;
    const int sw = w * 512;

    auto stageA = [&](int t, int h) {
        unsigned short* lp = S + ((t & 1) * 16384 + h * 8192 + sw);
        const unsigned short* gp = gA0 + (size_t)h * 128 * KDIM + t * 64;
        GLOAD_LDS16(gp, lp);
        GLOAD_LDS16(gp + (size_t)64 * KDIM, lp + 4096);
    };
    auto stageB = [&](int t, int h) {
        unsigned short* lp = Sb + ((t & 1) * 16384 + h * 8192 + sw);
        const unsigned short* gp = gB0 + (size_t)h * 128 * KDIM + t * 64;
        GLOAD_LDS16(gp, lp);
        GLOAD_LDS16(gp + (size_t)64 * KDIM, lp + 4096);
    };

    f32x4 acc[8][4];
#pragma unroll
    for (int m = 0; m < 8; ++m)
#pragma unroll
        for (int n = 0; n < 4; ++n)
            acc[m][n] = (f32x4){0.f, 0.f, 0.f, 0.f};
    bf16x8 afr[4][2];
    bf16x8 bfr[2][2][2];

    // prologue: tile0 full + B(1,h0), A(1,h0); wait tile0 (8 loads) landed
    stageA(0, 0); stageA(0, 1); stageB(0, 0); stageB(0, 1);
    stageB(1, 0); stageA(1, 0);
    asm volatile("s_waitcnt vmcnt(4)" ::: "memory");
    __builtin_amdgcn_s_barrier();

#pragma unroll 2
    for (int j = 0; j < 32; ++j) {
        const int jb = j & 1;
        PH(jb, 0, 0, 1, 1, { if (j < 31) stageB(j + 1, 1); }, );
        PH(jb, 0, 1, 0, 1, { if (j < 31) stageA(j + 1, 1); }, );
        PH(jb, 1, 0, 1, 0, { if (j < 30) stageB(j + 2, 0); }, );
        PH(jb, 1, 1, 0, 0, { if (j < 30) stageA(j + 2, 0); },
           { if (j < 30) { asm volatile("s_waitcnt vmcnt(4)" ::: "memory"); }
             else        { asm volatile("s_waitcnt vmcnt(0)" ::: "memory"); } });
    }

    // ---- fused LoRA: stage Wg[256][32] + Bc[256][32] linear, one K=32 step
    {
        const int lw_row = w * 16 + (l >> 2);
        const int lw_col = (l & 3) * 8;
        unsigned short* lpA = S + sw;
        const unsigned short* gpA = Wg + (size_t)(m0 + lw_row) * 32 + lw_col;
        GLOAD_LDS16(gpA, lpA);
        GLOAD_LDS16(gpA + (size_t)128 * 32, lpA + 4096);
        unsigned short* lpB = Sb + sw;
        const unsigned short* gpB = Bc + (size_t)(n0 + lw_row) * 32 + lw_col;
        GLOAD_LDS16(gpB, lpB);
        GLOAD_LDS16(gpB + (size_t)128 * 32, lpB + 4096);
    }
    asm volatile("s_waitcnt vmcnt(0)" ::: "memory");
    __builtin_amdgcn_s_barrier();

#pragma unroll
    for (int m = 0; m < 8; ++m) {
        bf16x8 af = *(const bf16x8*)&S[((m >> 2) * 128 + wr * 64 + (m & 3) * 16 + l15) * 32 + l16h * 8];
#pragma unroll
        for (int n = 0; n < 4; ++n) {
            bf16x8 bf = *(const bf16x8*)&Sb[((n >> 1) * 128 + wc * 32 + (n & 1) * 16 + l15) * 32 + l16h * 8];
            acc[m][n] = __builtin_amdgcn_mfma_f32_16x16x32_bf16(af, bf, acc[m][n], 0, 0, 0);
        }
    }

    // ---- bias + store fp32 ----
#pragma unroll
    for (int n = 0; n < 4; ++n) {
        const int cn = n0 + (n >> 1) * 128 + wc * 32 + (n & 1) * 16 + l15;
        const float bv = bias[cn];
#pragma unroll
        for (int m = 0; m < 8; ++m) {
            const int rm = m0 + (m >> 2) * 128 + wr * 64 + (m & 3) * 16 + l16h * 4;
#pragma unroll
            for (int jj = 0; jj < 4; ++jj)
                out[(size_t)(rm + jj) * NDIM + cn] = acc[m][n][jj] + bv;
        }
    }
}

// ---------------------------------------------------------------------------
extern "C" void kernel_launch(void* const* d_in, const int* in_sizes, int n_in,
                              void* d_out, int out_size, void* d_ws, size_t ws_size,
                              hipStream_t stream) {
    const float* x      = (const float*)d_in[0];
    const float* base_w = (const float*)d_in[1];
    const float* base_b = (const float*)d_in[2];
    const float* A      = (const float*)d_in[3];
    const float* Bm     = (const float*)d_in[4];
    const float* rw     = (const float*)d_in[5];
    float* out = (float*)d_out;

    char* ws = (char*)d_ws;
    unsigned short* xb  = (unsigned short*)(ws);                            // 33,554,432 B
    unsigned short* wb  = (unsigned short*)(ws + 33554432);                 //  8,388,608 B
    unsigned short* W36 = (unsigned short*)(ws + 33554432 + 8388608);       //    196,608 B
    unsigned short* Wg  = (unsigned short*)(ws + 33554432 + 8388608 + 196608);           // 524,288 B
    unsigned short* Bc  = (unsigned short*)(ws + 33554432 + 8388608 + 196608 + 524288);  // 131,072 B

    k_convert<<<dim3(2048), dim3(256), 0,      stream>>>(x, base_w, A, rw, Bm, xb, wb, W36, Bc);
    k_proj   <<<dim3(512),  dim3(64),  0,      stream>>>(xb, W36, Wg);
    k_gemm   <<<dim3(256),  dim3(512), 131072, stream>>>(xb, wb, Wg, Bc, base_b, out);
}

// Round 6
// 206.738 us; speedup vs baseline: 1.7777x; 1.0589x over previous
//
#include <hip/hip_runtime.h>
#include <hip/hip_bf16.h>
#include <stdint.h>

// MoELoRALinear: out = x@W^T + b + sum_e softmax(x@rw^T)_e * SCALE * (x@A_e^T)@B_e^T
// M=8192, K=2048, N=2048, E=4, R=8. SCALE = 2.
#define M_ROWS 8192
#define KDIM   2048
#define NDIM   2048
#define SCALE_F 2.0f

typedef __attribute__((ext_vector_type(8))) short  bf16x8;
typedef __attribute__((ext_vector_type(4))) float  f32x4;
typedef __attribute__((ext_vector_type(8))) unsigned short u16x8;

__device__ __forceinline__ unsigned short f2bf(float f) {
    unsigned u = __float_as_uint(f);
    unsigned r = (u + 0x7fffu + ((u >> 16) & 1u)) >> 16;  // RNE
    return (unsigned short)r;
}

#define GLOAD_LDS16(gptr, lptr) \
    __builtin_amdgcn_global_load_lds((const __attribute__((address_space(1))) void*)(gptr), \
                                     (__attribute__((address_space(3))) void*)(lptr), 16, 0, 0)

// ---------------------------------------------------------------------------
// Kernel 1: streaming converts (no x pass). base_w->wb bf16; pack
// W36[48][2048] = [A(32); rw(4); zeros(12)]; Bm[e][o][r] -> Bc[o][e*8+r].
// MUST run before k_proj (produces W36).
// ---------------------------------------------------------------------------
__global__ __launch_bounds__(256) void k_convert(
    const float* __restrict__ bw,
    const float* __restrict__ A,
    const float* __restrict__ rw,
    const float* __restrict__ Bm,
    unsigned short* __restrict__ wb,
    unsigned short* __restrict__ W36,
    unsigned short* __restrict__ Bc)
{
    const int t = blockIdx.x * 256 + threadIdx.x;
    const int nthr = gridDim.x * 256;

    for (int i = t; i < (NDIM * KDIM / 8); i += nthr) {
        float4 v0 = *(const float4*)(bw + (size_t)i * 8);
        float4 v1 = *(const float4*)(bw + (size_t)i * 8 + 4);
        u16x8 o = { f2bf(v0.x), f2bf(v0.y), f2bf(v0.z), f2bf(v0.w),
                    f2bf(v1.x), f2bf(v1.y), f2bf(v1.z), f2bf(v1.w) };
        *(u16x8*)(wb + (size_t)i * 8) = o;
    }
    if (t < 48 * 2048 / 8) {
        const int row = (t * 8) >> 11, col = (t * 8) & 2047;
        u16x8 o;
        if (row < 36) {
            const float* src = (row < 32) ? (A + (size_t)row * 2048 + col)
                                          : (rw + (size_t)(row - 32) * 2048 + col);
            float4 v0 = *(const float4*)(src);
            float4 v1 = *(const float4*)(src + 4);
            o = (u16x8){ f2bf(v0.x), f2bf(v0.y), f2bf(v0.z), f2bf(v0.w),
                         f2bf(v1.x), f2bf(v1.y), f2bf(v1.z), f2bf(v1.w) };
        } else {
            o = (u16x8){0, 0, 0, 0, 0, 0, 0, 0};
        }
        *(u16x8*)(W36 + (size_t)t * 8) = o;
    }
    if (t < 4 * 2048) {
        const int e = t >> 11, o = t & 2047;
        const float* src = Bm + ((size_t)e * 2048 + o) * 8;
        float4 v0 = *(const float4*)(src);
        float4 v1 = *(const float4*)(src + 4);
        u16x8 ov = { f2bf(v0.x), f2bf(v0.y), f2bf(v0.z), f2bf(v0.w),
                     f2bf(v1.x), f2bf(v1.y), f2bf(v1.z), f2bf(v1.w) };
        *(u16x8*)(Bc + (size_t)o * 32 + e * 8) = ov;
    }
}

// ---------------------------------------------------------------------------
// Kernel 2: fused x-convert + skinny GEMM, K-split 4 ways for TLP.
// Block = 256 thr (4 waves) on 16 rows; wave w covers k in [w*512,(w+1)*512):
// reads x fp32, converts, writes xb, accumulates partial P = x@W36^T.
// 12KB LDS partial-reduce; wave 0 does softmax-gate epilogue -> Wg.
// grid = 512 -> 8 waves/CU.
// ---------------------------------------------------------------------------
__global__ __launch_bounds__(256) void k_proj(
    const float* __restrict__ x,             // [8192][2048] fp32
    const unsigned short* __restrict__ W36,  // [48][2048]   bf16
    unsigned short* __restrict__ xb,         // [8192][2048] bf16 (out)
    unsigned short* __restrict__ Wg)         // [8192][32]   bf16 (out)
{
    __shared__ float red[3][4][64][4];       // 12KB

    const int tid = threadIdx.x;
    const int l = tid & 63, w = tid >> 6;
    const int l15 = l & 15, l16h = l >> 4;
    const int row0 = blockIdx.x * 16;
    const int kbase = w * 512;

    const float* pa = x + (size_t)(row0 + l15) * KDIM + kbase + l16h * 8;
    unsigned short* pxb = xb + (size_t)(row0 + l15) * KDIM + kbase + l16h * 8;
    const unsigned short* pb0 = W36 + (size_t)(0 * 16 + l15) * KDIM + kbase + l16h * 8;
    const unsigned short* pb1 = W36 + (size_t)(1 * 16 + l15) * KDIM + kbase + l16h * 8;
    const unsigned short* pb2 = W36 + (size_t)(2 * 16 + l15) * KDIM + kbase + l16h * 8;

    f32x4 acc[3];
#pragma unroll
    for (int n = 0; n < 3; ++n) acc[n] = (f32x4){0.f, 0.f, 0.f, 0.f};

#pragma unroll 4
    for (int kt = 0; kt < 16; ++kt) {        // 16 x 32 = 512 k per wave
        float4 va0 = *(const float4*)(pa + kt * 32);
        float4 va1 = *(const float4*)(pa + kt * 32 + 4);
        bf16x8 a = { (short)f2bf(va0.x), (short)f2bf(va0.y),
                     (short)f2bf(va0.z), (short)f2bf(va0.w),
                     (short)f2bf(va1.x), (short)f2bf(va1.y),
                     (short)f2bf(va1.z), (short)f2bf(va1.w) };
        *(bf16x8*)(pxb + kt * 32) = a;
        bf16x8 b0 = *(const bf16x8*)(pb0 + kt * 32);
        bf16x8 b1 = *(const bf16x8*)(pb1 + kt * 32);
        bf16x8 b2 = *(const bf16x8*)(pb2 + kt * 32);
        acc[0] = __builtin_amdgcn_mfma_f32_16x16x32_bf16(a, b0, acc[0], 0, 0, 0);
        acc[1] = __builtin_amdgcn_mfma_f32_16x16x32_bf16(a, b1, acc[1], 0, 0, 0);
        acc[2] = __builtin_amdgcn_mfma_f32_16x16x32_bf16(a, b2, acc[2], 0, 0, 0);
    }

#pragma unroll
    for (int n = 0; n < 3; ++n)
#pragma unroll
        for (int j = 0; j < 4; ++j)
            red[n][w][l][j] = acc[n][j];
    __syncthreads();

    if (w == 0) {
#pragma unroll
        for (int n = 0; n < 3; ++n)
#pragma unroll
            for (int j = 0; j < 4; ++j)
                acc[n][j] = red[n][0][l][j] + red[n][1][l][j]
                          + red[n][2][l][j] + red[n][3][l][j];

        // gating. C/D: col=l&15, row=(l>>4)*4+j. acc[2] cols 32..35 = logits.
#pragma unroll
        for (int j = 0; j < 4; ++j) {
            const int base = l & 48;
            float lg0 = __shfl(acc[2][j], base + 0);
            float lg1 = __shfl(acc[2][j], base + 1);
            float lg2 = __shfl(acc[2][j], base + 2);
            float lg3 = __shfl(acc[2][j], base + 3);
            float mx = fmaxf(fmaxf(lg0, lg1), fmaxf(lg2, lg3));
            float e0 = __expf(lg0 - mx), e1 = __expf(lg1 - mx);
            float e2 = __expf(lg2 - mx), e3 = __expf(lg3 - mx);
            float inv = SCALE_F / (e0 + e1 + e2 + e3);
            float g0 = e0 * inv, g1 = e1 * inv, g2 = e2 * inv, g3 = e3 * inv;

            const int row = row0 + l16h * 4 + j;
#pragma unroll
            for (int n = 0; n < 2; ++n) {
                const int cn = n * 16 + l15;
                const int e = cn >> 3;
                float g = (e == 0) ? g0 : (e == 1) ? g1 : (e == 2) ? g2 : g3;
                Wg[(size_t)row * 32 + cn] = f2bf(g * acc[n][j]);
            }
        }
    }
}

// ---------------------------------------------------------------------------
// Kernel 3: 256x256 8-phase GEMM, schedule v5. BK=64, 512 thr (8 waves 2x4),
// 128KB LDS (A 2buf x 2half x [128][64] at 0; B same at +32768 shorts).
// Per-phase reads balanced 8/4/8/4 (B-h0 of next tile prefetch-read in q3's
// post-ckpt shadow); MFMA kk-OUTER (acc dep distance 8); counted vmcnt(4)
// once per K-tile; raw barriers; setprio around MFMA cluster.
// Iter j (c=j&1, d=c^1), compute order (A0B0)(A0B1)(A1B1)(A1B0):
//   q0: rd A0(c);           stage B(j+1,h1)->d
//   q1: rd B1(c);           stage A(j+1,h1)->d
//   q2: rd A1(c);           stage B(j+2,h0)->c   [B(c,h0) pre-read q3(j-1)]
//   q3: stage A(j+2,h0)->c; ckpt vmcnt(4); MFMA; rd B0(d) prefetch
// Fused LoRA (K=32) + bias epilogue. grid = 256, XCD-chunked.
// ---------------------------------------------------------------------------
#define RD_A(C, H) do { _Pragma("unroll") for (int mi = 0; mi < 4; ++mi) {     \
      afr[mi][0] = *(const bf16x8*)&S[(C)*16384 + (H)*8192 + mi*1024 + aoff0]; \
      afr[mi][1] = *(const bf16x8*)&S[(C)*16384 + (H)*8192 + mi*1024 + aoff1]; \
    } } while (0)

#define RD_B(C, H) do { _Pragma("unroll") for (int ni = 0; ni < 2; ++ni) {     \
      bfr[H][ni][0] = *(const bf16x8*)&Sb[(C)*16384 + (H)*8192 + ni*1024 + boff0]; \
      bfr[H][ni][1] = *(const bf16x8*)&Sb[(C)*16384 + (H)*8192 + ni*1024 + boff1]; \
    } } while (0)

#define MFMA16(AH, BH) do {                                                    \
    __builtin_amdgcn_s_setprio(1);                                             \
    _Pragma("unroll") for (int kk = 0; kk < 2; ++kk)                           \
      _Pragma("unroll") for (int mi = 0; mi < 4; ++mi)                         \
        _Pragma("unroll") for (int ni = 0; ni < 2; ++ni)                       \
          acc[(AH)*4+mi][(BH)*2+ni] = __builtin_amdgcn_mfma_f32_16x16x32_bf16( \
            afr[mi][kk], bfr[BH][ni][kk], acc[(AH)*4+mi][(BH)*2+ni], 0, 0, 0); \
    __builtin_amdgcn_s_setprio(0);                                             \
  } while (0)

#define BAR() __builtin_amdgcn_s_barrier()

__global__ __launch_bounds__(512, 2) void k_gemm(
    const unsigned short* __restrict__ xb,   // [M][2048] bf16
    const unsigned short* __restrict__ wb,   // [N][2048] bf16
    const unsigned short* __restrict__ Wg,   // [M][32]   bf16
    const unsigned short* __restrict__ Bc,   // [N][32]   bf16
    const float* __restrict__ bias,          // [N]
    float* __restrict__ out)                 // [M][N] fp32
{
    extern __shared__ unsigned short S[];    // 65536 shorts = 128KB
    unsigned short* Sb = S + 32768;

    const int tid = threadIdx.x;
    const int l = tid & 63, w = tid >> 6;
    const int l15 = l & 15, l16h = l >> 4, l7 = l & 7;
    const int wr = w >> 2, wc = w & 3;

    const int bid = blockIdx.x;
    const int tile = (bid & 7) * 32 + (bid >> 3);
    const int mt = tile >> 3, nt = tile & 7;
    const int m0 = mt * 256, n0 = nt * 256;

    const int aoff0 = (wr * 64 + l15) * 64 + ((l16h ^ l7) << 3);
    const int aoff1 = (wr * 64 + l15) * 64 + (((4 + l16h) ^ l7) << 3);
    const int boff0 = (wc * 32 + l15) * 64 + ((l16h ^ l7) << 3);
    const int boff1 = (wc * 32 + l15) * 64 + (((4 + l16h) ^ l7) << 3);

    const int st_row = w * 8 + (l >> 3);
    const int st_col = ((l & 7) ^ (l >> 3)) * 8;
    const unsigned short* gA0 = xb + (size_t)(m0 + st_row) * KDIM + st_col;
    const unsigned short* gB0 = wb + (size_t)(n0 + st_row) * KDIM + st_col;
    const int sw = w * 512;

    auto stageA = [&](int t, int h) {
        unsigned short* lp = S + ((t & 1) * 16384 + h * 8192 + sw);
        const unsigned short* gp = gA0 + (size_t)h * 128 * KDIM + t * 64;
        GLOAD_LDS16(gp, lp);
        GLOAD_LDS16(gp + (size_t)64 * KDIM, lp + 4096);
    };
    auto stageB = [&](int t, int h) {
        unsigned short* lp = Sb + ((t & 1) * 16384 + h * 8192 + sw);
        const unsigned short* gp = gB0 + (size_t)h * 128 * KDIM + t * 64;
        GLOAD_LDS16(gp, lp);
        GLOAD_LDS16(gp + (size_t)64 * KDIM, lp + 4096);
    };

    f32x4 acc[8][4];
#pragma unroll
    for (int m = 0; m < 8; ++m)
#pragma unroll
        for (int n = 0; n < 4; ++n)
            acc[m][n] = (f32x4){0.f, 0.f, 0.f, 0.f};
    bf16x8 afr[4][2];
    bf16x8 bfr[2][2][2];

    // prologue: T0 all 4 halves + B(1,h0) + A(1,h0); drain T0; pre-read B0(buf0)
    stageA(0, 0); stageA(0, 1); stageB(0, 0); stageB(0, 1);
    stageB(1, 0); stageA(1, 0);
    asm volatile("s_waitcnt vmcnt(4)" ::: "memory");
    BAR();
    RD_B(0, 0);

#pragma unroll 2
    for (int j = 0; j < 32; ++j) {
        const int c = j & 1, d = c ^ 1;
        // q0: compute (A0,B0) — B0 pre-read; read A0 here
        RD_A(c, 0);
        if (j < 31) stageB(j + 1, 1);
        BAR(); MFMA16(0, 0); BAR();
        // q1: compute (A0,B1)
        RD_B(c, 1);
        if (j < 31) stageA(j + 1, 1);
        BAR(); MFMA16(0, 1); BAR();
        // q2: compute (A1,B1)
        RD_A(c, 1);
        if (j < 30) stageB(j + 2, 0);
        BAR(); MFMA16(1, 1); BAR();
        // q3: compute (A1,B0); ckpt; prefetch next tile's B0 after MFMA
        if (j < 30) stageA(j + 2, 0);
        if (j < 30)      { asm volatile("s_waitcnt vmcnt(4)" ::: "memory"); }
        else if (j == 30){ asm volatile("s_waitcnt vmcnt(0)" ::: "memory"); }
        BAR(); MFMA16(1, 0);
        if (j < 31) RD_B(d, 0);
        BAR();
    }

    // ---- fused LoRA: stage Wg[256][32] + Bc[256][32] linear, one K=32 step
    {
        const int lw_row = w * 16 + (l >> 2);
        const int lw_col = (l & 3) * 8;
        unsigned short* lpA = S + sw;
        const unsigned short* gpA = Wg + (size_t)(m0 + lw_row) * 32 + lw_col;
        GLOAD_LDS16(gpA, lpA);
        GLOAD_LDS16(gpA + (size_t)128 * 32, lpA + 4096);
        unsigned short* lpB = Sb + sw;
        const unsigned short* gpB = Bc + (size_t)(n0 + lw_row) * 32 + lw_col;
        GLOAD_LDS16(gpB, lpB);
        GLOAD_LDS16(gpB + (size_t)128 * 32, lpB + 4096);
    }
    asm volatile("s_waitcnt vmcnt(0)" ::: "memory");
    BAR();

#pragma unroll
    for (int m = 0; m < 8; ++m) {
        bf16x8 af = *(const bf16x8*)&S[((m >> 2) * 128 + wr * 64 + (m & 3) * 16 + l15) * 32 + l16h * 8];
#pragma unroll
        for (int n = 0; n < 4; ++n) {
            bf16x8 bf = *(const bf16x8*)&Sb[((n >> 1) * 128 + wc * 32 + (n & 1) * 16 + l15) * 32 + l16h * 8];
            acc[m][n] = __builtin_amdgcn_mfma_f32_16x16x32_bf16(af, bf, acc[m][n], 0, 0, 0);
        }
    }

    // ---- bias + store fp32 ----
#pragma unroll
    for (int n = 0; n < 4; ++n) {
        const int cn = n0 + (n >> 1) * 128 + wc * 32 + (n & 1) * 16 + l15;
        const float bv = bias[cn];
#pragma unroll
        for (int m = 0; m < 8; ++m) {
            const int rm = m0 + (m >> 2) * 128 + wr * 64 + (m & 3) * 16 + l16h * 4;
#pragma unroll
            for (int jj = 0; jj < 4; ++jj)
                out[(size_t)(rm + jj) * NDIM + cn] = acc[m][n][jj] + bv;
        }
    }
}

// ---------------------------------------------------------------------------
extern "C" void kernel_launch(void* const* d_in, const int* in_sizes, int n_in,
                              void* d_out, int out_size, void* d_ws, size_t ws_size,
                              hipStream_t stream) {
    const float* x      = (const float*)d_in[0];
    const float* base_w = (const float*)d_in[1];
    const float* base_b = (const float*)d_in[2];
    const float* A      = (const float*)d_in[3];
    const float* Bm     = (const float*)d_in[4];
    const float* rw     = (const float*)d_in[5];
    float* out = (float*)d_out;

    char* ws = (char*)d_ws;
    unsigned short* xb  = (unsigned short*)(ws);                            // 33,554,432 B
    unsigned short* wb  = (unsigned short*)(ws + 33554432);                 //  8,388,608 B
    unsigned short* W36 = (unsigned short*)(ws + 33554432 + 8388608);       //    196,608 B
    unsigned short* Wg  = (unsigned short*)(ws + 33554432 + 8388608 + 196608);           // 524,288 B
    unsigned short* Bc  = (unsigned short*)(ws + 33554432 + 8388608 + 196608 + 524288);  // 131,072 B

    // ORDER MATTERS: k_convert produces W36, consumed by k_proj.
    k_convert<<<dim3(512), dim3(256), 0,      stream>>>(base_w, A, rw, Bm, wb, W36, Bc);
    k_proj   <<<dim3(512), dim3(256), 0,      stream>>>(x, W36, xb, Wg);
    k_gemm   <<<dim3(256), dim3(512), 131072, stream>>>(xb, wb, Wg, Bc, base_b, out);
}